// Round 1
// baseline (181.009 us; speedup 1.0000x reference)
//
#include <hip/hip_runtime.h>
#include <math.h>

#define BB 8
#define NCC 1024
#define NTT 1024
#define HH 128
#define DYY 32
#define NCHUNK 8
#define CHUNK_N (NCC / NCHUNK)   /* 128 */
#define NTG (BB * (NTT / 64))    /* 128 target-groups of 64 */

// ---------------- K1: h1 = relu(xt @ W0 + b0), xt:(8192,3), W0:(3,128) ----------------
__global__ void k_layer0(const float* __restrict__ xt, const float* __restrict__ W0,
                         const float* __restrict__ b0, float* __restrict__ h1) {
    int gid = blockIdx.x * blockDim.x + threadIdx.x;   // 0 .. 8192*128
    int p = gid >> 7, j = gid & 127;
    float x0 = xt[p * 3 + 0], x1 = xt[p * 3 + 1], x2 = xt[p * 3 + 2];
    float acc = b0[j];
    acc = fmaf(W0[0 * HH + j], x0, acc);
    acc = fmaf(W0[1 * HH + j], x1, acc);
    acc = fmaf(W0[2 * HH + j], x2, acc);
    h1[gid] = fmaxf(acc, 0.f);
}

// ---------------- K2/K3: hout = relu(hin @ W + b), W:(128,128) ----------------
// thread j holds W[:,j] in 128 VGPRs; h-row loads are wave-uniform (scalarizable).
__global__ __launch_bounds__(256) void k_layer(const float* __restrict__ hin,
                                               const float* __restrict__ W,
                                               const float* __restrict__ bias,
                                               float* __restrict__ hout) {
    int j = threadIdx.x & 127;
    int slot = threadIdx.x >> 7;
    int pbase = blockIdx.x * 16 + slot * 8;
    float wcol[HH];
#pragma unroll
    for (int k = 0; k < HH; ++k) wcol[k] = W[k * HH + j];
    float bj = bias[j];
    for (int pt = 0; pt < 8; ++pt) {
        const float* __restrict__ h = hin + (size_t)(pbase + pt) * HH;
        float acc = bj;
#pragma unroll
        for (int k = 0; k < HH; ++k) acc = fmaf(wcol[k], h[k], acc);
        hout[(size_t)(pbase + pt) * HH + j] = fmaxf(acc, 0.f);
    }
}

// ---------------- K4: attention partials over an n-chunk ----------------
// lane = one target; prologue does layer3 (h3 @ W3 + b3) + exp -> sig.
// P<=0 always (sig>0, squares>=0) so no max-subtraction: e=exp(P)<=1, partials
// over n-chunks merge by plain summation.
__global__ __launch_bounds__(64) void k_attn(const float* __restrict__ xc,
                                             const float* __restrict__ yc,
                                             const float* __restrict__ xt,
                                             const float* __restrict__ h3,
                                             const float* __restrict__ W3,
                                             const float* __restrict__ b3,
                                             float* __restrict__ pO,
                                             float* __restrict__ pl) {
    int lane = threadIdx.x;        // 0..63
    int tg = blockIdx.x;           // 0..127
    int chunk = blockIdx.y;        // 0..7
    int b = tg >> 4;
    size_t bt = (size_t)b * NTT + (size_t)(tg & 15) * 64 + lane;

    // layer3 + exp (amortized over the 128-n loop below)
    const float* __restrict__ h = h3 + bt * HH;
    float y0 = b3[0], y1 = b3[1], y2 = b3[2];
#pragma unroll
    for (int k = 0; k < HH; ++k) {
        float hv = h[k];
        y0 = fmaf(W3[k * 3 + 0], hv, y0);
        y1 = fmaf(W3[k * 3 + 1], hv, y1);
        y2 = fmaf(W3[k * 3 + 2], hv, y2);
    }
    float s0 = __expf(y0), s1 = __expf(y1), s2 = __expf(y2);

    float a0 = xt[bt * 3 + 0], a1 = xt[bt * 3 + 1], a2 = xt[bt * 3 + 2];
    float acc[DYY];
#pragma unroll
    for (int d = 0; d < DYY; ++d) acc[d] = 0.f;
    float l = 0.f;

    const float* __restrict__ xcb = xc + ((size_t)b * NCC + (size_t)chunk * CHUNK_N) * 3;
    const float* __restrict__ ycb = yc + ((size_t)b * NCC + (size_t)chunk * CHUNK_N) * DYY;
#pragma unroll 2
    for (int nn = 0; nn < CHUNK_N; ++nn) {
        float d0 = xcb[nn * 3 + 0] - a0;
        float d1 = xcb[nn * 3 + 1] - a1;
        float d2 = xcb[nn * 3 + 2] - a2;
        float p = fmaf(s0, d0 * d0, fmaf(s1, d1 * d1, s2 * (d2 * d2)));
        float e = __expf(-p);
        l += e;
#pragma unroll
        for (int d = 0; d < DYY; ++d) acc[d] = fmaf(e, ycb[nn * DYY + d], acc[d]);
    }

    float* __restrict__ o = pO + (((size_t)tg * NCHUNK + chunk) * 64 + lane) * DYY;
#pragma unroll
    for (int d = 0; d < DYY; ++d) o[d] = acc[d];
    pl[((size_t)tg * NCHUNK + chunk) * 64 + lane] = l;
}

// ---------------- K5: combine partials, normalize ----------------
__global__ void k_combine(const float* __restrict__ pO, const float* __restrict__ pl,
                          float* __restrict__ out) {
    int gid = blockIdx.x * blockDim.x + threadIdx.x;   // 0..262143, flat (b,t,d)
    int tg = gid >> 11;          // (b, tgroup)
    int tl = (gid >> 5) & 63;    // target within group
    int d = gid & 31;
    float s = 0.f, ls = 0.f;
#pragma unroll
    for (int c = 0; c < NCHUNK; ++c) {
        s  += pO[(((size_t)tg * NCHUNK + c) * 64 + tl) * DYY + d];
        ls += pl[((size_t)tg * NCHUNK + c) * 64 + tl];
    }
    out[gid] = s / ls;
}

extern "C" void kernel_launch(void* const* d_in, const int* in_sizes, int n_in,
                              void* d_out, int out_size, void* d_ws, size_t ws_size,
                              hipStream_t stream) {
    const float* xc = (const float*)d_in[0];
    const float* yc = (const float*)d_in[1];
    const float* xt = (const float*)d_in[2];
    const float* W0 = (const float*)d_in[3];
    const float* b0 = (const float*)d_in[4];
    const float* W1 = (const float*)d_in[5];
    const float* b1 = (const float*)d_in[6];
    const float* W2 = (const float*)d_in[7];
    const float* b2 = (const float*)d_in[8];
    const float* W3 = (const float*)d_in[9];
    const float* b3 = (const float*)d_in[10];
    float* out = (float*)d_out;

    // workspace layout (floats): h1[1M] h2[1M] h3[1M] pO[2M] pl[64K]  ~= 21.2 MB
    float* ws = (float*)d_ws;
    float* h1 = ws;
    float* h2 = h1 + (size_t)BB * NTT * HH;
    float* h3 = h2 + (size_t)BB * NTT * HH;
    float* pO = h3 + (size_t)BB * NTT * HH;
    float* pl = pO + (size_t)NTG * NCHUNK * 64 * DYY;

    k_layer0<<<dim3((BB * NTT * HH) / 256), dim3(256), 0, stream>>>(xt, W0, b0, h1);
    k_layer<<<dim3(512), dim3(256), 0, stream>>>(h1, W1, b1, h2);
    k_layer<<<dim3(512), dim3(256), 0, stream>>>(h2, W2, b2, h3);
    k_attn<<<dim3(NTG, NCHUNK), dim3(64), 0, stream>>>(xc, yc, xt, h3, W3, b3, pO, pl);
    k_combine<<<dim3(out_size / 256), dim3(256), 0, stream>>>(pO, pl, out);
}